// Round 6
// baseline (76.891 us; speedup 1.0000x reference)
//
#include <hip/hip_runtime.h>

#define CIN   32
#define COUT  64
#define XG    256
#define ZG    256
#define K     16
#define CHUNK 256    // points scanned per wave

// Each wave owns one height bin b and a 256-point chunk of the point list.
// Weights for bin b live in 32 VGPRs (w[i] = kern[b][i][lane], lane = cout).
// The wave scans its chunk's coords; points whose idx==b are processed via
// a uniform ballot/ffs loop: broadcast feats via __shfl, 32 reg-FMAs, one
// atomic scatter-add into the BEV grid.
__global__ __launch_bounds__(256, 6) void tobev_kernel(
    const float* __restrict__ feats,
    const int*   __restrict__ coords,
    const float* __restrict__ kern,
    float* __restrict__ out,
    int n, int nchunks)
{
    const int g    = blockIdx.x * 4 + (threadIdx.x >> 6);   // global wave id
    const int lane = threadIdx.x & 63;
    const int b    = g / nchunks;                           // this wave's height bin
    const int chunk = g - b * nchunks;
    if (b >= K) return;

    // Stage bin-b weights in registers: one column per lane (lane = cout).
    float w[CIN];
    #pragma unroll
    for (int i = 0; i < CIN; ++i)
        w[i] = kern[(size_t)b * (CIN * COUT) + i * COUT + lane];

    const int base = chunk * CHUNK;

    for (int j = 0; j < CHUNK / 64; ++j) {
        const int p = base + j * 64 + lane;
        int idx = -1, lin = 0;
        if (p < n) {
            const int4 c = *reinterpret_cast<const int4*>(coords + (size_t)p * 4);
            idx = c.y;                                      // STRIDE == 1
            lin = (c.w * XG + c.x) * ZG + c.z;
        }
        unsigned long long mask = __ballot(idx == b);
        while (mask) {                                      // uniform loop
            const int s = __ffsll(mask) - 1;
            mask &= mask - 1;
            const int   ps   = base + j * 64 + s;           // wave-uniform point id
            const int   lins = __shfl(lin, s, 64);
            const float f    = feats[(size_t)ps * CIN + (lane & 31)];
            float acc = 0.f;
            #pragma unroll
            for (int i = 0; i < CIN; ++i)
                acc = fmaf(__shfl(f, i, 64), w[i], acc);
            unsafeAtomicAdd(&out[(size_t)lins * COUT + lane], acc);
        }
    }
}

extern "C" void kernel_launch(void* const* d_in, const int* in_sizes, int n_in,
                              void* d_out, int out_size, void* d_ws, size_t ws_size,
                              hipStream_t stream) {
    const float* feats  = (const float*)d_in[0];
    const int*   coords = (const int*)d_in[1];
    const float* kern   = (const float*)d_in[2];
    float* out = (float*)d_out;

    const int n = in_sizes[0] / CIN;                        // N = 100000

    // segment_sum accumulator must start at zero every call
    hipMemsetAsync(d_out, 0, (size_t)out_size * sizeof(float), stream);

    const int nchunks = (n + CHUNK - 1) / CHUNK;            // chunks per bin
    const int nwaves  = K * nchunks;
    const int blocks  = (nwaves + 3) / 4;                   // 4 waves per block
    hipLaunchKernelGGL(tobev_kernel, dim3(blocks), dim3(256), 0, stream,
                       feats, coords, kern, out, n, nchunks);
}

// Round 11
// 76.248 us; speedup vs baseline: 1.0084x; 1.0084x over previous
//
#include <hip/hip_runtime.h>

#define CIN    32
#define COUT   64
#define XG     256
#define ZG     256
#define K      16
#define NSEG   (4 * 256 * 256)   // B*X*Z = 262144 output segments
#define MAXPPB 8                 // slot capacity per segment
#define MAX_OVF 4096

// ---------------- Phase A: bin points by output segment ----------------
// counts[lin]++ (int atomic), slots[lin][pos] = (heightBin<<20 | pointId).
__global__ __launch_bounds__(256) void phaseA(
    const int* __restrict__ coords,
    int* __restrict__ counts, int* __restrict__ slots, int* __restrict__ ovf,
    int n)
{
    const int p = blockIdx.x * 256 + threadIdx.x;
    if (p >= n) return;
    const int4 c = *reinterpret_cast<const int4*>(coords + (size_t)p * 4);
    const int lin = (c.w * XG + c.x) * ZG + c.z;
    const int packed = (c.y << 20) | p;                 // idx:4b | pid:17b
    const int pos = atomicAdd(&counts[lin], 1);
    if (pos < MAXPPB) {
        slots[(size_t)lin * MAXPPB + pos] = packed;
    } else {
        const int o = atomicAdd(&ovf[0], 1);
        if (o < MAX_OVF) { ovf[64 + 2*o] = lin; ovf[64 + 2*o + 1] = packed; }
    }
}

// ---------------- Phase B: gather per segment, streaming stores --------
// 1024 threads = 16 waves; each wave owns 32 consecutive segments.
// Bins 0..7 staged in 64 KiB LDS; bins 8..15 read from L2.
__global__ __launch_bounds__(1024) void phaseB(
    const float* __restrict__ feats,
    const float* __restrict__ kern,
    const int* __restrict__ counts, const int* __restrict__ slots,
    float* __restrict__ out)
{
    __shared__ float wl[8 * CIN * COUT];                // 64 KiB
    for (int j = threadIdx.x; j < 8 * CIN * COUT; j += 1024)
        wl[j] = kern[j];
    __syncthreads();

    const int wv   = threadIdx.x >> 6;                  // 0..15
    const int lane = threadIdx.x & 63;                  // lane = cout
    const int segBase = blockIdx.x * 512 + wv * 32;

    for (int s = 0; s < 32; ++s) {
        const int seg = segBase + s;
        int cnt = counts[seg];
        if (cnt > MAXPPB) cnt = MAXPPB;
        float acc = 0.f;
        for (int q = 0; q < cnt; ++q) {
            const int packed = slots[(size_t)seg * MAXPPB + q];
            const int pid = packed & 0xFFFFF;
            const int idx = packed >> 20;
            const float f = feats[(size_t)pid * CIN + (lane & 31)];
            if (idx < 8) {
                const float* __restrict__ w = &wl[idx * (CIN * COUT) + lane];
                #pragma unroll
                for (int i = 0; i < CIN; ++i)
                    acc = fmaf(__shfl(f, i, 64), w[(size_t)i * COUT], acc);
            } else {
                const float* __restrict__ w = &kern[(size_t)idx * (CIN * COUT) + lane];
                #pragma unroll
                for (int i = 0; i < CIN; ++i)
                    acc = fmaf(__shfl(f, i, 64), w[(size_t)i * COUT], acc);
            }
        }
        out[(size_t)seg * COUT + lane] = acc;           // plain coalesced store
    }
}

// ---------------- Phase C: overflow mop-up (normally 0 entries) --------
__global__ __launch_bounds__(256) void phaseC(
    const float* __restrict__ feats,
    const float* __restrict__ kern,
    const int* __restrict__ ovf,
    float* __restrict__ out)
{
    int nov = ovf[0];
    if (nov > MAX_OVF) nov = MAX_OVF;
    const int wv   = threadIdx.x >> 6;
    const int lane = threadIdx.x & 63;
    for (int e = wv; e < nov; e += 4) {
        const int lin    = ovf[64 + 2*e];
        const int packed = ovf[64 + 2*e + 1];
        const int pid = packed & 0xFFFFF;
        const int idx = packed >> 20;
        const float f = feats[(size_t)pid * CIN + (lane & 31)];
        const float* __restrict__ w = &kern[(size_t)idx * (CIN * COUT) + lane];
        float acc = 0.f;
        #pragma unroll
        for (int i = 0; i < CIN; ++i)
            acc = fmaf(__shfl(f, i, 64), w[(size_t)i * COUT], acc);
        unsafeAtomicAdd(&out[(size_t)lin * COUT + lane], acc);
    }
}

// ---------------- Fallback: proven round-2 atomic scatter --------------
__global__ __launch_bounds__(256) void tobev_atomic(
    const float* __restrict__ feats,
    const int*   __restrict__ coords,
    const float* __restrict__ kern,
    float* __restrict__ out,
    int n)
{
    const int wid  = blockIdx.x * 4 + (threadIdx.x >> 6);
    const int lane = threadIdx.x & 63;
    if (wid >= n) return;
    const int4 c = *reinterpret_cast<const int4*>(coords + (size_t)wid * 4);
    const int idx = c.y;
    const int lin = (c.w * XG + c.x) * ZG + c.z;
    const float f = feats[(size_t)wid * CIN + (lane & 31)];
    const float* __restrict__ w = kern + (size_t)idx * (CIN * COUT) + lane;
    float acc = 0.f;
    #pragma unroll
    for (int i = 0; i < CIN; ++i)
        acc = fmaf(__shfl(f, i, 64), w[(size_t)i * COUT], acc);
    unsafeAtomicAdd(&out[(size_t)lin * COUT + lane], acc);
}

extern "C" void kernel_launch(void* const* d_in, const int* in_sizes, int n_in,
                              void* d_out, int out_size, void* d_ws, size_t ws_size,
                              hipStream_t stream) {
    const float* feats  = (const float*)d_in[0];
    const int*   coords = (const int*)d_in[1];
    const float* kern   = (const float*)d_in[2];
    float* out = (float*)d_out;
    const int n = in_sizes[0] / CIN;                    // N = 100000

    // ws layout (dwords): [counts: NSEG][ovf_cnt+pad: 64][ovf: 2*MAX_OVF][slots: NSEG*MAXPPB]
    const size_t needed = ((size_t)NSEG + 64 + 2 * MAX_OVF + (size_t)NSEG * MAXPPB) * 4;

    if (ws_size >= needed) {
        int* ws     = (int*)d_ws;
        int* counts = ws;
        int* ovf    = ws + NSEG;
        int* slots  = ws + NSEG + 64 + 2 * MAX_OVF;

        hipMemsetAsync(counts, 0, ((size_t)NSEG + 64) * 4, stream);   // counts + ovf_cnt
        hipLaunchKernelGGL(phaseA, dim3((n + 255) / 256), dim3(256), 0, stream,
                           coords, counts, slots, ovf, n);
        hipLaunchKernelGGL(phaseB, dim3(NSEG / 512), dim3(1024), 0, stream,
                           feats, kern, counts, slots, out);
        hipLaunchKernelGGL(phaseC, dim3(1), dim3(256), 0, stream,
                           feats, kern, ovf, out);
    } else {
        hipMemsetAsync(d_out, 0, (size_t)out_size * sizeof(float), stream);
        hipLaunchKernelGGL(tobev_atomic, dim3((n + 3) / 4), dim3(256), 0, stream,
                           feats, coords, kern, out, n);
    }
}